// Round 5
// baseline (356.771 us; speedup 1.0000x reference)
//
#include <hip/hip_runtime.h>
#include <hip/hip_bf16.h>

typedef __bf16 bf16_t;
typedef __bf16 bf16x2 __attribute__((ext_vector_type(2)));
typedef __bf16 bf16x4v __attribute__((ext_vector_type(4)));
typedef __bf16 bf16x8 __attribute__((ext_vector_type(8)));
typedef float f32x4 __attribute__((ext_vector_type(4)));

#define LOG2E 1.4426950408889634f
// (1/sqrt(128)) * log2(e), folded into Q at ln_rope time
#define QSCALE (0.08838834764831843f * 1.4426950408889634f)

// ---------------- fp32 -> bf16 conversion ----------------
__global__ __launch_bounds__(256) void cvt_f32_bf16(const float* __restrict__ in,
                                                    bf16_t* __restrict__ out, int n4) {
  int i = blockIdx.x * 256 + threadIdx.x;
  if (i < n4) {
    float4 v = ((const float4*)in)[i];
    bf16x4v o;
    o[0] = (__bf16)v.x; o[1] = (__bf16)v.y; o[2] = (__bf16)v.z; o[3] = (__bf16)v.w;
    *(bf16x4v*)(out + (size_t)i * 4) = o;
  }
}

// ---------------- RoPE cos/sin tables: [S=2048][64] ----------------
__global__ __launch_bounds__(256) void rope_tables(float* __restrict__ cosT,
                                                   float* __restrict__ sinT) {
  int idx = blockIdx.x * 256 + threadIdx.x;   // 2048*64 = 131072
  int s = idx >> 6, i = idx & 63;
  float inv = __builtin_amdgcn_exp2f(-(float)i * (19.931568569324174f / 64.0f));
  float f = (float)s * inv;
  cosT[idx] = cosf(f);
  sinT[idx] = sinf(f);
}

// ---------------- bf16 NT GEMM: C[m,n] = sum_k A[m,k]*B[n,k], fp32 out ----------
// BM=128, BN=256, BK=64; 512 threads = 8 waves (2 M x 4 N), per-wave 64x64.
// Triple-buffered LDS (3 x 48KB), 2-tile stage lookahead, one barrier/K-tile,
// counted vmcnt(6) (never 0 in main loop). Full-row XOR swizzle pc = lc^(row&7)
// applied on BOTH sides: pre-swizzled global source + swizzled ds_read offset.
__global__ __launch_bounds__(512) void gemm8(const bf16_t* __restrict__ A,
                                             const bf16_t* __restrict__ B,
                                             float* __restrict__ C,
                                             int M, int N, int K) {
  __shared__ bf16_t LA[3][128 * 64];
  __shared__ bf16_t LB[3][256 * 64];
  int nb = N >> 8;
  int cpx = gridDim.x >> 3;                 // grid divisible by 8 (XCD swizzle)
  int bid = blockIdx.x;
  int swz = (bid & 7) * cpx + (bid >> 3);
  int bm = swz / nb, bn = swz % nb;
  int m0 = bm << 7, n0 = bn << 8;
  int tid = threadIdx.x, lane = tid & 63, wv = tid >> 6;
  int wr = wv >> 2, wc = wv & 3, lr = lane & 15, g = lane >> 4;
  int T = K >> 6;

  // stage one K-tile (A 2 insts + B 4 insts per thread) into buffer bi
  auto stage = [&](int kt, int bi) {
    int k0 = kt << 6;
#pragma unroll
    for (int i = 0; i < 2; i++) {
      int c = i * 512 + tid;                      // physical 16B chunk index
      int row = c >> 3, lc = (c & 7) ^ (row & 7); // logical col-chunk
      __builtin_amdgcn_global_load_lds(
          (const __attribute__((address_space(1))) void*)(A + (size_t)(m0 + row) * K + k0 + lc * 8),
          (__attribute__((address_space(3))) void*)&LA[bi][(i * 512 + wv * 64) * 8], 16, 0, 0);
    }
#pragma unroll
    for (int i = 0; i < 4; i++) {
      int c = i * 512 + tid;
      int row = c >> 3, lc = (c & 7) ^ (row & 7);
      __builtin_amdgcn_global_load_lds(
          (const __attribute__((address_space(1))) void*)(B + (size_t)(n0 + row) * K + k0 + lc * 8),
          (__attribute__((address_space(3))) void*)&LB[bi][(i * 512 + wv * 64) * 8], 16, 0, 0);
    }
  };

  f32x4 acc[4][4];
#pragma unroll
  for (int i = 0; i < 4; i++)
#pragma unroll
    for (int j = 0; j < 4; j++)
#pragma unroll
      for (int r = 0; r < 4; r++) acc[i][j][r] = 0.f;

  stage(0, 0);
  stage(1, 1);

  int offA = (wr * 64 + lr) * 64;           // + mi*16*64
  int offB = (wc * 64 + lr) * 64;           // + ni*16*64
  int ofk0 = ((0 + g) ^ (lr & 7)) << 3;     // ks=0 swizzled chunk (bf16 units)
  int ofk1 = ((4 + g) ^ (lr & 7)) << 3;     // ks=1

  int bi = 0;
  for (int t = 0; t < T; t++) {
    asm volatile("s_waitcnt lgkmcnt(0)" ::: "memory");  // my reads of buf[(t-1)%3] done
    asm volatile("s_waitcnt vmcnt(6)" ::: "memory");    // tile t fully landed
    __builtin_amdgcn_s_barrier();
    int kt2 = t + 2;
    int b2 = bi + 2; if (b2 >= 3) b2 -= 3;
    stage(kt2 < T ? kt2 : 0, b2);                       // 2-tile lookahead (dummy at tail)
    const bf16_t* la = LA[bi];
    const bf16_t* lb = LB[bi];
#pragma unroll
    for (int ks = 0; ks < 2; ks++) {
      int ofk = ks ? ofk1 : ofk0;
      bf16x8 af[4], bfv[4];
#pragma unroll
      for (int mi = 0; mi < 4; mi++) af[mi] = *(const bf16x8*)&la[offA + mi * 1024 + ofk];
#pragma unroll
      for (int ni = 0; ni < 4; ni++) bfv[ni] = *(const bf16x8*)&lb[offB + ni * 1024 + ofk];
      __builtin_amdgcn_s_setprio(1);
#pragma unroll
      for (int mi = 0; mi < 4; mi++)
#pragma unroll
        for (int ni = 0; ni < 4; ni++)
          acc[mi][ni] = __builtin_amdgcn_mfma_f32_16x16x32_bf16(af[mi], bfv[ni], acc[mi][ni], 0, 0, 0);
      __builtin_amdgcn_s_setprio(0);
    }
    bi += 1; if (bi >= 3) bi = 0;
  }

#pragma unroll
  for (int mi = 0; mi < 4; mi++)
#pragma unroll
    for (int ni = 0; ni < 4; ni++) {
      int m = m0 + wr * 64 + mi * 16 + g * 4;
      int n = n0 + wc * 64 + ni * 16 + lr;
#pragma unroll
      for (int r = 0; r < 4; r++) C[(size_t)(m + r) * N + n] = acc[mi][ni][r];
    }
}

// ---------------- fused per-head LayerNorm + RoPE -> bf16 Q(B,H,S,D), K(B,KV,S,D) ----
// Q is pre-scaled by QSCALE so attention's QK^T lands directly in exp2-domain.
__global__ __launch_bounds__(256) void ln_rope(const float* __restrict__ qkv,
                                               const float* __restrict__ qw, const float* __restrict__ qb,
                                               const float* __restrict__ kw, const float* __restrict__ kb,
                                               const float* __restrict__ cosT, const float* __restrict__ sinT,
                                               bf16_t* __restrict__ Qr, bf16_t* __restrict__ Kr) {
  int row = blockIdx.x;              // b*2048 + s
  int b = row >> 11, s = row & 2047;
  int lane = threadIdx.x & 63, wv = threadIdx.x >> 6;
  float c = cosT[(s << 6) + lane], sn = sinT[(s << 6) + lane];
  const float* base = qkv + (size_t)row * 5120;
#pragma unroll
  for (int i = 0; i < 5; i++) {
    int head = wv * 5 + i;           // 0..15 = q heads, 16..19 = k heads
    bool isq = head < 16;
    int off = isq ? (head << 7) : (4096 + ((head - 16) << 7));
    float2 x = *(const float2*)(base + off + (lane << 1));
    float sum = x.x + x.y;
#pragma unroll
    for (int m = 1; m < 64; m <<= 1) sum += __shfl_xor(sum, m);
    float mu = sum * 0.0078125f;
    float x0 = x.x - mu, x1 = x.y - mu;
    float vs = x0 * x0 + x1 * x1;
#pragma unroll
    for (int m = 1; m < 64; m <<= 1) vs += __shfl_xor(vs, m);
    float rs = rsqrtf(vs * 0.0078125f + 1e-6f);
    const float* w = isq ? qw : kw;
    const float* bb = isq ? qb : kb;
    float y0 = x0 * rs * w[lane << 1] + bb[lane << 1];
    float y1 = x1 * rs * w[(lane << 1) + 1] + bb[(lane << 1) + 1];
    float o0 = y0 * c - y1 * sn;
    float o1 = y0 * sn + y1 * c;
    if (isq) { o0 *= QSCALE; o1 *= QSCALE; }
    bf16x2 ov; ov[0] = (__bf16)o0; ov[1] = (__bf16)o1;
    size_t dst = isq ? ((((size_t)(b * 16 + head)) * 2048 + s) * 128 + (lane << 1))
                     : ((((size_t)(b * 4 + (head - 16))) * 2048 + s) * 128 + (lane << 1));
    *(bf16x2*)((isq ? Qr : Kr) + dst) = ov;
  }
}

// ---------------- V transpose: qkv v-slice (B,S,KV,D) -> Vt (B,KV,D,S) bf16 -------
__global__ __launch_bounds__(256) void vtrans(const float* __restrict__ qkv,
                                              bf16_t* __restrict__ Vt) {
  int bid = blockIdx.x;              // ((b*4+kv)*64 + sb)
  int sb = bid & 63, kv = (bid >> 6) & 3, b = bid >> 8;
  int s0 = sb << 5;
  __shared__ bf16_t T[128 * 33];
  int tid = threadIdx.x;
#pragma unroll
  for (int i = 0; i < 16; i++) {
    int idx = i * 256 + tid;         // 0..4095
    int r = idx >> 7, d = idx & 127;
    float v = qkv[((size_t)(b * 2048 + s0 + r)) * 5120 + 4608 + (kv << 7) + d];
    T[d * 33 + r] = (__bf16)v;
  }
  __syncthreads();
#pragma unroll
  for (int j = 0; j < 16; j++) {
    int idx = j * 256 + tid;
    int d = idx >> 5, sc = idx & 31;
    Vt[(((size_t)(b * 4 + kv)) * 128 + d) * 2048 + s0 + sc] = T[d * 33 + sc];
  }
}

// ---------------- causal GQA flash attention + sigmoid gate -> ag bf16 (B,S,H*D) ----
// Softmax: lane-local common path (defer-max, per-lane lsum partials; cross-lane
// shfls only on rare rescale + once in epilogue). Only the diagonal half-tile
// (h==qg) applies the causal mask. K fragments double-banked (kA/kB) so next
// half-tile's loads are in flight during current compute.
__global__ __launch_bounds__(256) void attn(const bf16_t* __restrict__ Qr,
                                            const bf16_t* __restrict__ Kr,
                                            const bf16_t* __restrict__ Vt,
                                            const float* __restrict__ qkv,
                                            bf16_t* __restrict__ ag) {
  int bid = blockIdx.x;                 // 512 = 16h * 2b * 16jj  (jj high bits: longest first)
  int h = bid & 15, b = (bid >> 4) & 1, jj = bid >> 5;
  int kvh = h >> 2;
  int tid = threadIdx.x, lane = tid & 63, wv = tid >> 6;
  int lr = lane & 15, g = lane >> 4;
  int qg = (wv & 2) ? (63 - 2 * jj - (wv & 1)) : (2 * jj + (wv & 1));
  int qw = qg << 5;                     // wave q base (32 rows)
  int qrow0 = qw + lr, qrow1 = qrow0 + 16;
  int nh = qg + 1;                      // 32-wide kv half-tiles: kvb = 0..32*qg

  const bf16_t* Qg0 = Qr + (((size_t)(b * 16 + h)) * 2048 + qrow0) * 128;
  bf16x8 qf0[4], qf1[4];
#pragma unroll
  for (int ds = 0; ds < 4; ds++) {
    qf0[ds] = *(const bf16x8*)(Qg0 + ds * 32 + g * 8);
    qf1[ds] = *(const bf16x8*)(Qg0 + 16 * 128 + ds * 32 + g * 8);
  }
  const bf16_t* Kg = Kr + ((size_t)(b * 4 + kvh)) * 2048 * 128;
  const bf16_t* Vg = Vt + ((size_t)(b * 4 + kvh)) * 128 * 2048;

  f32x4 oa0[8], oa1[8];
#pragma unroll
  for (int i = 0; i < 8; i++)
#pragma unroll
    for (int r = 0; r < 4; r++) { oa0[i][r] = 0.f; oa1[i][r] = 0.f; }
  float mrun0 = -1e30f, mrun1 = -1e30f, lsp0 = 0.f, lsp1 = 0.f;

  int r0base = ((lr >> 2) << 3) + (lr & 3);       // pi(lr): A-row -> K-row map
  int kvlane = g << 3;                            // this lane's kv slot base within half-tile

  bf16x8 kA[8], kB[8], va[8];

  auto loadK = [&](bf16x8 (&ka)[8], int kvb) {
    const bf16_t* kp = Kg + (size_t)(kvb + r0base) * 128 + g * 8;
#pragma unroll
    for (int ds = 0; ds < 4; ds++) {
      ka[ds]     = *(const bf16x8*)(kp + ds * 32);
      ka[4 + ds] = *(const bf16x8*)(kp + 4 * 128 + ds * 32);
    }
  };

  // softmax update for one q-frag; dia = needs causal mask
  auto sm = [&](const f32x4& s0, const f32x4& s1, int qrow, int kvabs, bool dia,
                float& mrun, float& lsp, bf16x8& pb, f32x4 (&oac)[8]) {
    float tt[8];
#pragma unroll
    for (int r = 0; r < 4; r++) { tt[r] = s0[r]; tt[4 + r] = s1[r]; }
    if (dia) {
#pragma unroll
      for (int r = 0; r < 4; r++) {
        if (kvabs + r > qrow)     tt[r]     = -1e30f;
        if (kvabs + 4 + r > qrow) tt[4 + r] = -1e30f;
      }
    }
    float lm = fmaxf(fmaxf(fmaxf(tt[0], tt[1]), tt[2]),
                     fmaxf(fmaxf(tt[3], tt[4]), fmaxf(fmaxf(tt[5], tt[6]), tt[7])));
    if (__all(lm <= mrun + 8.f)) {      // defer-max common path: lane-local only
      float ps = 0.f;
#pragma unroll
      for (int i = 0; i < 8; i++) {
        float pv = __builtin_amdgcn_exp2f(tt[i] - mrun);
        pb[i] = (__bf16)pv; ps += pv;
      }
      lsp += ps;
    } else {                            // rare rescale path
      float pm = lm;
      pm = fmaxf(pm, __shfl_xor(pm, 16));
      pm = fmaxf(pm, __shfl_xor(pm, 32));
      float mnew = fmaxf(mrun, pm);
      float corr = __builtin_amdgcn_exp2f(mrun - mnew);
      float ps = 0.f;
#pragma unroll
      for (int i = 0; i < 8; i++) {
        float pv = __builtin_amdgcn_exp2f(tt[i] - mnew);
        pb[i] = (__bf16)pv; ps += pv;
      }
      lsp = lsp * corr + ps;
      mrun = mnew;
#pragma unroll
      for (int dt = 0; dt < 8; dt++)
#pragma unroll
        for (int r = 0; r < 4; r++) oac[dt][r] *= corr;
    }
  };

  auto half = [&](bf16x8 (&ka)[8], int hh) {
    int kvb = hh << 5;
    const bf16_t* vp = Vg + (size_t)lr * 2048 + kvb + g * 8;
#pragma unroll
    for (int dt = 0; dt < 8; dt++)
      va[dt] = *(const bf16x8*)(vp + (size_t)dt * 16 * 2048);
    f32x4 s00, s10, s01, s11;
#pragma unroll
    for (int r = 0; r < 4; r++) { s00[r] = 0.f; s10[r] = 0.f; s01[r] = 0.f; s11[r] = 0.f; }
    __builtin_amdgcn_s_setprio(1);
#pragma unroll
    for (int ds = 0; ds < 4; ds++) {
      s00 = __builtin_amdgcn_mfma_f32_16x16x32_bf16(ka[ds],     qf0[ds], s00, 0, 0, 0);
      s10 = __builtin_amdgcn_mfma_f32_16x16x32_bf16(ka[4 + ds], qf0[ds], s10, 0, 0, 0);
      s01 = __builtin_amdgcn_mfma_f32_16x16x32_bf16(ka[ds],     qf1[ds], s01, 0, 0, 0);
      s11 = __builtin_amdgcn_mfma_f32_16x16x32_bf16(ka[4 + ds], qf1[ds], s11, 0, 0, 0);
    }
    __builtin_amdgcn_s_setprio(0);
    int kvabs = kvb + kvlane;
    bool dia = (hh == qg);
    bf16x8 pb0, pb1;
    sm(s00, s10, qrow0, kvabs, dia, mrun0, lsp0, pb0, oa0);
    sm(s01, s11, qrow1, kvabs, dia, mrun1, lsp1, pb1, oa1);
    __builtin_amdgcn_s_setprio(1);
#pragma unroll
    for (int dt = 0; dt < 8; dt++) {
      oa0[dt] = __builtin_amdgcn_mfma_f32_16x16x32_bf16(va[dt], pb0, oa0[dt], 0, 0, 0);
      oa1[dt] = __builtin_amdgcn_mfma_f32_16x16x32_bf16(va[dt], pb1, oa1[dt], 0, 0, 0);
    }
    __builtin_amdgcn_s_setprio(0);
  };

  loadK(kA, 0);
  int hh = 0;
  for (; hh + 1 < nh; hh += 2) {
    loadK(kB, (hh + 1) << 5);
    half(kA, hh);
    if (hh + 2 < nh) loadK(kA, (hh + 2) << 5);
    half(kB, hh + 1);
  }
  if (hh < nh) half(kA, hh);

  // epilogue: row-reduce per-lane lsum partials (lanes lr, lr+16, lr+32, lr+48)
  float ls0 = lsp0 + __shfl_xor(lsp0, 16);
  ls0 += __shfl_xor(ls0, 32);
  float ls1 = lsp1 + __shfl_xor(lsp1, 16);
  ls1 += __shfl_xor(ls1, 32);
  float invl0 = __builtin_amdgcn_rcpf(ls0);
  float invl1 = __builtin_amdgcn_rcpf(ls1);

  size_t ob0 = ((size_t)b * 2048 + qrow0) * 2048 + (h << 7);
  size_t gb0 = ((size_t)b * 2048 + qrow0) * 5120 + 2048 + (h << 7);
  size_t ob1 = ((size_t)b * 2048 + qrow1) * 2048 + (h << 7);
  size_t gb1 = ((size_t)b * 2048 + qrow1) * 5120 + 2048 + (h << 7);
#pragma unroll
  for (int dt = 0; dt < 8; dt++) {
    int d = dt * 16 + (g << 2);
    float4 gt0 = *(const float4*)(qkv + gb0 + d);
    float4 gt1 = *(const float4*)(qkv + gb1 + d);
    bf16x4v o0, o1;
    o0[0] = (__bf16)(oa0[dt][0] * invl0 * __builtin_amdgcn_rcpf(1.f + __builtin_amdgcn_exp2f(-gt0.x * LOG2E)));
    o0[1] = (__bf16)(oa0[dt][1] * invl0 * __builtin_amdgcn_rcpf(1.f + __builtin_amdgcn_exp2f(-gt0.y * LOG2E)));
    o0[2] = (__bf16)(oa0[dt][2] * invl0 * __builtin_amdgcn_rcpf(1.f + __builtin_amdgcn_exp2f(-gt0.z * LOG2E)));
    o0[3] = (__bf16)(oa0[dt][3] * invl0 * __builtin_amdgcn_rcpf(1.f + __builtin_amdgcn_exp2f(-gt0.w * LOG2E)));
    o1[0] = (__bf16)(oa1[dt][0] * invl1 * __builtin_amdgcn_rcpf(1.f + __builtin_amdgcn_exp2f(-gt1.x * LOG2E)));
    o1[1] = (__bf16)(oa1[dt][1] * invl1 * __builtin_amdgcn_rcpf(1.f + __builtin_amdgcn_exp2f(-gt1.y * LOG2E)));
    o1[2] = (__bf16)(oa1[dt][2] * invl1 * __builtin_amdgcn_rcpf(1.f + __builtin_amdgcn_exp2f(-gt1.z * LOG2E)));
    o1[3] = (__bf16)(oa1[dt][3] * invl1 * __builtin_amdgcn_rcpf(1.f + __builtin_amdgcn_exp2f(-gt1.w * LOG2E)));
    *(bf16x4v*)(ag + ob0 + d) = o0;
    *(bf16x4v*)(ag + ob1 + d) = o1;
  }
}

// ---------------- launch ----------------
extern "C" void kernel_launch(void* const* d_in, const int* in_sizes, int n_in,
                              void* d_out, int out_size, void* d_ws, size_t ws_size,
                              hipStream_t stream) {
  const float* x    = (const float*)d_in[0];
  const float* wqkv = (const float*)d_in[1];
  const float* wo   = (const float*)d_in[2];
  const float* qnw  = (const float*)d_in[3];
  const float* qnb  = (const float*)d_in[4];
  const float* knw  = (const float*)d_in[5];
  const float* knb  = (const float*)d_in[6];
  float* out = (float*)d_out;

  char* p = (char*)d_ws;
  bf16_t* xb  = (bf16_t*)p;           // 16 MB, reused as ag after GEMM1
  bf16_t* ag  = xb;
  p += (size_t)16777216;
  bf16_t* wqb = (bf16_t*)p;           // 20 MB, reused as Qr after GEMM1
  bf16_t* Qr  = wqb;
  p += (size_t)20971520;
  bf16_t* wob = (bf16_t*)p; p += (size_t)8388608;
  float*  qkv = (float*)p;  p += (size_t)83886080;
  bf16_t* Kr  = (bf16_t*)p; p += (size_t)4194304;
  bf16_t* Vt  = (bf16_t*)p; p += (size_t)4194304;
  float* cosT = (float*)p;  p += (size_t)524288;
  float* sinT = (float*)p;  p += (size_t)524288;

  cvt_f32_bf16<<<8192, 256, 0, stream>>>(x, xb, 2097152);
  cvt_f32_bf16<<<10240, 256, 0, stream>>>(wqkv, wqb, 2621440);
  cvt_f32_bf16<<<4096, 256, 0, stream>>>(wo, wob, 1048576);
  rope_tables<<<512, 256, 0, stream>>>(cosT, sinT);

  // qkv = x @ w_qkv^T   (4096 x 5120 x K=2048)
  gemm8<<<640, 512, 0, stream>>>(xb, wqb, qkv, 4096, 5120, 2048);

  ln_rope<<<4096, 256, 0, stream>>>(qkv, qnw, qnb, knw, knb, cosT, sinT, Qr, Kr);
  vtrans<<<512, 256, 0, stream>>>(qkv, Vt);

  attn<<<512, 256, 0, stream>>>(Qr, Kr, Vt, qkv, ag);

  // out = ag @ w_o^T    (4096 x 2048 x K=2048)
  gemm8<<<256, 512, 0, stream>>>(ag, wob, out, 4096, 2048, 2048);
}

// Round 7
// 328.332 us; speedup vs baseline: 1.0866x; 1.0866x over previous
//
#include <hip/hip_runtime.h>
#include <hip/hip_bf16.h>

typedef __bf16 bf16_t;
typedef __bf16 bf16x2 __attribute__((ext_vector_type(2)));
typedef __bf16 bf16x4v __attribute__((ext_vector_type(4)));
typedef __bf16 bf16x8 __attribute__((ext_vector_type(8)));
typedef float f32x4 __attribute__((ext_vector_type(4)));

#define LOG2E 1.4426950408889634f
// (1/sqrt(128)) * log2(e), folded into Q at ln_rope time
#define QSCALE (0.08838834764831843f * 1.4426950408889634f)

// ---------------- fp32 -> bf16 conversion ----------------
__global__ __launch_bounds__(256) void cvt_f32_bf16(const float* __restrict__ in,
                                                    bf16_t* __restrict__ out, int n4) {
  int i = blockIdx.x * 256 + threadIdx.x;
  if (i < n4) {
    float4 v = ((const float4*)in)[i];
    bf16x4v o;
    o[0] = (__bf16)v.x; o[1] = (__bf16)v.y; o[2] = (__bf16)v.z; o[3] = (__bf16)v.w;
    *(bf16x4v*)(out + (size_t)i * 4) = o;
  }
}

// ---------------- RoPE cos/sin tables: [S=2048][64] ----------------
__global__ __launch_bounds__(256) void rope_tables(float* __restrict__ cosT,
                                                   float* __restrict__ sinT) {
  int idx = blockIdx.x * 256 + threadIdx.x;   // 2048*64 = 131072
  int s = idx >> 6, i = idx & 63;
  float inv = __builtin_amdgcn_exp2f(-(float)i * (19.931568569324174f / 64.0f));
  float f = (float)s * inv;
  cosT[idx] = cosf(f);
  sinT[idx] = sinf(f);
}

// ---------------- bf16 NT GEMM, phase-scheduled ----------------
// C[m,n] = sum_k A[m,k]*B[n,k], fp32 out. 512 threads = 8 waves (2M x 4N).
// BM = MI*32, BN = NI*64; per-wave output (MI*16) x (NI*16). BK=64, double-buffered.
// PH = MI/2 phases per K-tile. Phase 0: stage 3 insts -> vmcnt(3) -> BARRIER ->
// ds_read -> MFMA -> lgkm(0) -> barrier.  (vmcnt->barrier->read ordering is the
// correctness-critical part: each wave's vmcnt only certifies its OWN loads.)
// Phases >0: stage -> ds_read -> barrier -> MFMA -> lgkm(0) -> barrier.
template<int MI, int NI>
__global__ __launch_bounds__(512) void gemm8p(const bf16_t* __restrict__ A,
                                              const bf16_t* __restrict__ B,
                                              float* __restrict__ C,
                                              int M, int N, int K) {
  constexpr int BM = MI * 32;
  constexpr int BN = NI * 64;
  constexpr int NA = BM / 64;            // A stage insts per K-tile
  constexpr int NB = BN / 64;            // B stage insts per K-tile
  constexpr int ST = NA + NB;
  constexpr int PH = MI / 2;             // phases per K-tile (4 or 2)
  constexpr int stBase = ST / PH;
  constexpr int stFirst = ST - stBase * (PH - 1);   // == 3 for both configs
  static_assert(stFirst == 3, "vmcnt literal assumes 3 first-phase stages");

  __shared__ bf16_t LA[2][BM * 64];
  __shared__ bf16_t LB[2][BN * 64];

  int nb = N / BN;
  int cpx = gridDim.x >> 3;              // grid divisible by 8
  int bid = blockIdx.x;
  int swz = (bid & 7) * cpx + (bid >> 3);
  int bm = swz / nb, bn = swz % nb;
  int m0 = bm * BM, n0 = bn * BN;
  int tid = threadIdx.x, lane = tid & 63, wv = tid >> 6;
  int wr = wv >> 2, wc = wv & 3, lr = lane & 15, g = lane >> 4;
  int T = K >> 6;

  // stage instruction s of K-tile kt into buffer bi: s<NA -> A chunk, else B.
  // 512 lanes x 16B, linear LDS dest, inverse-swizzled global source.
  auto stageI = [&](int kt, int bi, int s) {
    int k0 = kt << 6;
    if (s < NA) {
      int c = s * 512 + tid;
      int row = c >> 3, lc = (c & 7) ^ (row & 7);
      __builtin_amdgcn_global_load_lds(
          (const __attribute__((address_space(1))) void*)(A + (size_t)(m0 + row) * K + k0 + lc * 8),
          (__attribute__((address_space(3))) void*)&LA[bi][(s * 512 + wv * 64) * 8], 16, 0, 0);
    } else {
      int c = (s - NA) * 512 + tid;
      int row = c >> 3, lc = (c & 7) ^ (row & 7);
      __builtin_amdgcn_global_load_lds(
          (const __attribute__((address_space(1))) void*)(B + (size_t)(n0 + row) * K + k0 + lc * 8),
          (__attribute__((address_space(3))) void*)&LB[bi][((s - NA) * 512 + wv * 64) * 8], 16, 0, 0);
    }
  };

  f32x4 acc[MI][NI];
#pragma unroll
  for (int i = 0; i < MI; i++)
#pragma unroll
    for (int j = 0; j < NI; j++)
#pragma unroll
      for (int r = 0; r < 4; r++) acc[i][j][r] = 0.f;

  // prologue: stage K-tile 0 into buf 0
#pragma unroll
  for (int s = 0; s < ST; s++) stageI(0, 0, s);

  int ofk0 = ((0 + g) ^ (lr & 7)) << 3;     // ks=0 swizzled chunk offset (bf16)
  int ofk1 = ((4 + g) ^ (lr & 7)) << 3;     // ks=1
  int offA = (wr * (MI * 16) + lr) * 64;
  int offB = (wc * (NI * 16) + lr) * 64;

  for (int t = 0; t < T; t++) {
    int bi = t & 1, bo = bi ^ 1;
    const bf16_t* la = LA[bi];
    const bf16_t* lb = LB[bi];
    bool pre = (t + 1 < T);
    bf16x8 bq[NI];
#pragma unroll
    for (int ph = 0; ph < PH; ph++) {
      const int s0 = (ph == 0) ? 0 : stFirst + (ph - 1) * stBase;
      const int sc = (ph == 0) ? stFirst : stBase;
      if (pre) {
#pragma unroll
        for (int s = s0; s < s0 + sc; s++) stageI(t + 1, bo, s);
      }
      if (ph == 0) {
        // my tile-t loads landed (3 of t+1 still in flight); then barrier so
        // EVERY wave's tile-t loads have landed before anyone reads.
        if (pre) asm volatile("s_waitcnt vmcnt(3)" ::: "memory");
        else     asm volatile("s_waitcnt vmcnt(0)" ::: "memory");
        __builtin_amdgcn_s_barrier();
        asm volatile("" ::: "memory");     // no load hoisting above the barrier
      }
      const int ks = (PH == 4) ? (ph >> 1) : ph;
      const int q  = (PH == 4) ? (ph & 1) : 0;
      const bool rb = (PH == 2) || ((ph & 1) == 0);
      const int ofk = ks ? ofk1 : ofk0;
      bf16x8 af[4];
#pragma unroll
      for (int i = 0; i < 4; i++)
        af[i] = *(const bf16x8*)&la[offA + (q * 4 + i) * 1024 + ofk];
      if (rb) {
#pragma unroll
        for (int ni = 0; ni < NI; ni++)
          bq[ni] = *(const bf16x8*)&lb[offB + ni * 1024 + ofk];
      }
      if (ph != 0) {
        asm volatile("" ::: "memory");
        __builtin_amdgcn_s_barrier();      // phase separation (reads already safe)
        asm volatile("" ::: "memory");
      }
      __builtin_amdgcn_s_setprio(1);
#pragma unroll
      for (int i = 0; i < 4; i++)
#pragma unroll
        for (int ni = 0; ni < NI; ni++)
          acc[q * 4 + i][ni] =
              __builtin_amdgcn_mfma_f32_16x16x32_bf16(af[i], bq[ni], acc[q * 4 + i][ni], 0, 0, 0);
      __builtin_amdgcn_s_setprio(0);
      asm volatile("s_waitcnt lgkmcnt(0)" ::: "memory");  // my ds_reads done before recycle
      __builtin_amdgcn_s_barrier();
      asm volatile("" ::: "memory");
    }
  }

#pragma unroll
  for (int mi = 0; mi < MI; mi++)
#pragma unroll
    for (int ni = 0; ni < NI; ni++) {
      int m = m0 + wr * (MI * 16) + mi * 16 + g * 4;
      int n = n0 + wc * (NI * 16) + ni * 16 + lr;
#pragma unroll
      for (int r = 0; r < 4; r++) C[(size_t)(m + r) * N + n] = acc[mi][ni][r];
    }
}

// ---------------- fused per-head LayerNorm + RoPE -> bf16 Q(B,H,S,D), K(B,KV,S,D) ----
// Q is pre-scaled by QSCALE so attention's QK^T lands directly in exp2-domain.
__global__ __launch_bounds__(256) void ln_rope(const float* __restrict__ qkv,
                                               const float* __restrict__ qw, const float* __restrict__ qb,
                                               const float* __restrict__ kw, const float* __restrict__ kb,
                                               const float* __restrict__ cosT, const float* __restrict__ sinT,
                                               bf16_t* __restrict__ Qr, bf16_t* __restrict__ Kr) {
  int row = blockIdx.x;              // b*2048 + s
  int b = row >> 11, s = row & 2047;
  int lane = threadIdx.x & 63, wv = threadIdx.x >> 6;
  float c = cosT[(s << 6) + lane], sn = sinT[(s << 6) + lane];
  const float* base = qkv + (size_t)row * 5120;
#pragma unroll
  for (int i = 0; i < 5; i++) {
    int head = wv * 5 + i;           // 0..15 = q heads, 16..19 = k heads
    bool isq = head < 16;
    int off = isq ? (head << 7) : (4096 + ((head - 16) << 7));
    float2 x = *(const float2*)(base + off + (lane << 1));
    float sum = x.x + x.y;
#pragma unroll
    for (int m = 1; m < 64; m <<= 1) sum += __shfl_xor(sum, m);
    float mu = sum * 0.0078125f;
    float x0 = x.x - mu, x1 = x.y - mu;
    float vs = x0 * x0 + x1 * x1;
#pragma unroll
    for (int m = 1; m < 64; m <<= 1) vs += __shfl_xor(vs, m);
    float rs = rsqrtf(vs * 0.0078125f + 1e-6f);
    const float* w = isq ? qw : kw;
    const float* bb = isq ? qb : kb;
    float y0 = x0 * rs * w[lane << 1] + bb[lane << 1];
    float y1 = x1 * rs * w[(lane << 1) + 1] + bb[(lane << 1) + 1];
    float o0 = y0 * c - y1 * sn;
    float o1 = y0 * sn + y1 * c;
    if (isq) { o0 *= QSCALE; o1 *= QSCALE; }
    bf16x2 ov; ov[0] = (__bf16)o0; ov[1] = (__bf16)o1;
    size_t dst = isq ? ((((size_t)(b * 16 + head)) * 2048 + s) * 128 + (lane << 1))
                     : ((((size_t)(b * 4 + (head - 16))) * 2048 + s) * 128 + (lane << 1));
    *(bf16x2*)((isq ? Qr : Kr) + dst) = ov;
  }
}

// ---------------- V transpose: qkv v-slice (B,S,KV,D) -> Vt (B,KV,D,S) bf16 -------
__global__ __launch_bounds__(256) void vtrans(const float* __restrict__ qkv,
                                              bf16_t* __restrict__ Vt) {
  int bid = blockIdx.x;              // ((b*4+kv)*64 + sb)
  int sb = bid & 63, kv = (bid >> 6) & 3, b = bid >> 8;
  int s0 = sb << 5;
  __shared__ bf16_t T[128 * 33];
  int tid = threadIdx.x;
#pragma unroll
  for (int i = 0; i < 16; i++) {
    int idx = i * 256 + tid;         // 0..4095
    int r = idx >> 7, d = idx & 127;
    float v = qkv[((size_t)(b * 2048 + s0 + r)) * 5120 + 4608 + (kv << 7) + d];
    T[d * 33 + r] = (__bf16)v;
  }
  __syncthreads();
#pragma unroll
  for (int j = 0; j < 16; j++) {
    int idx = j * 256 + tid;
    int d = idx >> 5, sc = idx & 31;
    Vt[(((size_t)(b * 4 + kv)) * 128 + d) * 2048 + s0 + sc] = T[d * 33 + sc];
  }
}

// ---------------- causal GQA flash attention + sigmoid gate -> ag bf16 (B,S,H*D) ----
__global__ __launch_bounds__(256) void attn(const bf16_t* __restrict__ Qr,
                                            const bf16_t* __restrict__ Kr,
                                            const bf16_t* __restrict__ Vt,
                                            const float* __restrict__ qkv,
                                            bf16_t* __restrict__ ag) {
  int bid = blockIdx.x;                 // 512 = 16h * 2b * 16jj
  int h = bid & 15, b = (bid >> 4) & 1, jj = bid >> 5;
  int kvh = h >> 2;
  int tid = threadIdx.x, lane = tid & 63, wv = tid >> 6;
  int lr = lane & 15, g = lane >> 4;
  int qg = (wv & 2) ? (63 - 2 * jj - (wv & 1)) : (2 * jj + (wv & 1));
  int qw = qg << 5;                     // wave q base (32 rows)
  int qrow0 = qw + lr, qrow1 = qrow0 + 16;
  int nh = qg + 1;                      // 32-wide kv half-tiles

  const bf16_t* Qg0 = Qr + (((size_t)(b * 16 + h)) * 2048 + qrow0) * 128;
  bf16x8 qf0[4], qf1[4];
#pragma unroll
  for (int ds = 0; ds < 4; ds++) {
    qf0[ds] = *(const bf16x8*)(Qg0 + ds * 32 + g * 8);
    qf1[ds] = *(const bf16x8*)(Qg0 + 16 * 128 + ds * 32 + g * 8);
  }
  const bf16_t* Kg = Kr + ((size_t)(b * 4 + kvh)) * 2048 * 128;
  const bf16_t* Vg = Vt + ((size_t)(b * 4 + kvh)) * 128 * 2048;

  f32x4 oa0[8], oa1[8];
#pragma unroll
  for (int i = 0; i < 8; i++)
#pragma unroll
    for (int r = 0; r < 4; r++) { oa0[i][r] = 0.f; oa1[i][r] = 0.f; }
  float mrun0 = -1e30f, mrun1 = -1e30f, lsp0 = 0.f, lsp1 = 0.f;

  int r0base = ((lr >> 2) << 3) + (lr & 3);       // pi(lr): A-row -> K-row map
  int kvlane = g << 3;

  bf16x8 kA[8], kB[8], va[8];

  auto loadK = [&](bf16x8 (&ka)[8], int kvb) {
    const bf16_t* kp = Kg + (size_t)(kvb + r0base) * 128 + g * 8;
#pragma unroll
    for (int ds = 0; ds < 4; ds++) {
      ka[ds]     = *(const bf16x8*)(kp + ds * 32);
      ka[4 + ds] = *(const bf16x8*)(kp + 4 * 128 + ds * 32);
    }
  };

  auto sm = [&](const f32x4& s0, const f32x4& s1, int qrow, int kvabs, bool dia,
                float& mrun, float& lsp, bf16x8& pb, f32x4 (&oac)[8]) {
    float tt[8];
#pragma unroll
    for (int r = 0; r < 4; r++) { tt[r] = s0[r]; tt[4 + r] = s1[r]; }
    if (dia) {
#pragma unroll
      for (int r = 0; r < 4; r++) {
        if (kvabs + r > qrow)     tt[r]     = -1e30f;
        if (kvabs + 4 + r > qrow) tt[4 + r] = -1e30f;
      }
    }
    float lm = fmaxf(fmaxf(fmaxf(tt[0], tt[1]), tt[2]),
                     fmaxf(fmaxf(tt[3], tt[4]), fmaxf(fmaxf(tt[5], tt[6]), tt[7])));
    if (__all(lm <= mrun + 8.f)) {      // defer-max common path: lane-local only
      float ps = 0.f;
#pragma unroll
      for (int i = 0; i < 8; i++) {
        float pv = __builtin_amdgcn_exp2f(tt[i] - mrun);
        pb[i] = (__bf16)pv; ps += pv;
      }
      lsp += ps;
    } else {                            // rare rescale path
      float pm = lm;
      pm = fmaxf(pm, __shfl_xor(pm, 16));
      pm = fmaxf(pm, __shfl_xor(pm, 32));
      float mnew = fmaxf(mrun, pm);
      float corr = __builtin_amdgcn_exp2f(mrun - mnew);
      float ps = 0.f;
#pragma unroll
      for (int i = 0; i < 8; i++) {
        float pv = __builtin_amdgcn_exp2f(tt[i] - mnew);
        pb[i] = (__bf16)pv; ps += pv;
      }
      lsp = lsp * corr + ps;
      mrun = mnew;
#pragma unroll
      for (int dt = 0; dt < 8; dt++)
#pragma unroll
        for (int r = 0; r < 4; r++) oac[dt][r] *= corr;
    }
  };

  auto half = [&](bf16x8 (&ka)[8], int hh) {
    int kvb = hh << 5;
    const bf16_t* vp = Vg + (size_t)lr * 2048 + kvb + g * 8;
#pragma unroll
    for (int dt = 0; dt < 8; dt++)
      va[dt] = *(const bf16x8*)(vp + (size_t)dt * 16 * 2048);
    f32x4 s00, s10, s01, s11;
#pragma unroll
    for (int r = 0; r < 4; r++) { s00[r] = 0.f; s10[r] = 0.f; s01[r] = 0.f; s11[r] = 0.f; }
    __builtin_amdgcn_s_setprio(1);
#pragma unroll
    for (int ds = 0; ds < 4; ds++) {
      s00 = __builtin_amdgcn_mfma_f32_16x16x32_bf16(ka[ds],     qf0[ds], s00, 0, 0, 0);
      s10 = __builtin_amdgcn_mfma_f32_16x16x32_bf16(ka[4 + ds], qf0[ds], s10, 0, 0, 0);
      s01 = __builtin_amdgcn_mfma_f32_16x16x32_bf16(ka[ds],     qf1[ds], s01, 0, 0, 0);
      s11 = __builtin_amdgcn_mfma_f32_16x16x32_bf16(ka[4 + ds], qf1[ds], s11, 0, 0, 0);
    }
    __builtin_amdgcn_s_setprio(0);
    int kvabs = kvb + kvlane;
    bool dia = (hh == qg);
    bf16x8 pb0, pb1;
    sm(s00, s10, qrow0, kvabs, dia, mrun0, lsp0, pb0, oa0);
    sm(s01, s11, qrow1, kvabs, dia, mrun1, lsp1, pb1, oa1);
    __builtin_amdgcn_s_setprio(1);
#pragma unroll
    for (int dt = 0; dt < 8; dt++) {
      oa0[dt] = __builtin_amdgcn_mfma_f32_16x16x32_bf16(va[dt], pb0, oa0[dt], 0, 0, 0);
      oa1[dt] = __builtin_amdgcn_mfma_f32_16x16x32_bf16(va[dt], pb1, oa1[dt], 0, 0, 0);
    }
    __builtin_amdgcn_s_setprio(0);
  };

  loadK(kA, 0);
  int hh = 0;
  for (; hh + 1 < nh; hh += 2) {
    loadK(kB, (hh + 1) << 5);
    half(kA, hh);
    if (hh + 2 < nh) loadK(kA, (hh + 2) << 5);
    half(kB, hh + 1);
  }
  if (hh < nh) half(kA, hh);

  float ls0 = lsp0 + __shfl_xor(lsp0, 16);
  ls0 += __shfl_xor(ls0, 32);
  float ls1 = lsp1 + __shfl_xor(lsp1, 16);
  ls1 += __shfl_xor(ls1, 32);
  float invl0 = __builtin_amdgcn_rcpf(ls0);
  float invl1 = __builtin_amdgcn_rcpf(ls1);

  size_t ob0 = ((size_t)b * 2048 + qrow0) * 2048 + (h << 7);
  size_t gb0 = ((size_t)b * 2048 + qrow0) * 5120 + 2048 + (h << 7);
  size_t ob1 = ((size_t)b * 2048 + qrow1) * 2048 + (h << 7);
  size_t gb1 = ((size_t)b * 2048 + qrow1) * 5120 + 2048 + (h << 7);
#pragma unroll
  for (int dt = 0; dt < 8; dt++) {
    int d = dt * 16 + (g << 2);
    float4 gt0 = *(const float4*)(qkv + gb0 + d);
    float4 gt1 = *(const float4*)(qkv + gb1 + d);
    bf16x4v o0, o1;
    o0[0] = (__bf16)(oa0[dt][0] * invl0 * __builtin_amdgcn_rcpf(1.f + __builtin_amdgcn_exp2f(-gt0.x * LOG2E)));
    o0[1] = (__bf16)(oa0[dt][1] * invl0 * __builtin_amdgcn_rcpf(1.f + __builtin_amdgcn_exp2f(-gt0.y * LOG2E)));
    o0[2] = (__bf16)(oa0[dt][2] * invl0 * __builtin_amdgcn_rcpf(1.f + __builtin_amdgcn_exp2f(-gt0.z * LOG2E)));
    o0[3] = (__bf16)(oa0[dt][3] * invl0 * __builtin_amdgcn_rcpf(1.f + __builtin_amdgcn_exp2f(-gt0.w * LOG2E)));
    o1[0] = (__bf16)(oa1[dt][0] * invl1 * __builtin_amdgcn_rcpf(1.f + __builtin_amdgcn_exp2f(-gt1.x * LOG2E)));
    o1[1] = (__bf16)(oa1[dt][1] * invl1 * __builtin_amdgcn_rcpf(1.f + __builtin_amdgcn_exp2f(-gt1.y * LOG2E)));
    o1[2] = (__bf16)(oa1[dt][2] * invl1 * __builtin_amdgcn_rcpf(1.f + __builtin_amdgcn_exp2f(-gt1.z * LOG2E)));
    o1[3] = (__bf16)(oa1[dt][3] * invl1 * __builtin_amdgcn_rcpf(1.f + __builtin_amdgcn_exp2f(-gt1.w * LOG2E)));
    *(bf16x4v*)(ag + ob0 + d) = o0;
    *(bf16x4v*)(ag + ob1 + d) = o1;
  }
}

// ---------------- launch ----------------
extern "C" void kernel_launch(void* const* d_in, const int* in_sizes, int n_in,
                              void* d_out, int out_size, void* d_ws, size_t ws_size,
                              hipStream_t stream) {
  const float* x    = (const float*)d_in[0];
  const float* wqkv = (const float*)d_in[1];
  const float* wo   = (const float*)d_in[2];
  const float* qnw  = (const float*)d_in[3];
  const float* qnb  = (const float*)d_in[4];
  const float* knw  = (const float*)d_in[5];
  const float* knb  = (const float*)d_in[6];
  float* out = (float*)d_out;

  char* p = (char*)d_ws;
  bf16_t* xb  = (bf16_t*)p;           // 16 MB, reused as ag after GEMM1
  bf16_t* ag  = xb;
  p += (size_t)16777216;
  bf16_t* wqb = (bf16_t*)p;           // 20 MB, reused as Qr after GEMM1
  bf16_t* Qr  = wqb;
  p += (size_t)20971520;
  bf16_t* wob = (bf16_t*)p; p += (size_t)8388608;
  float*  qkv = (float*)p;  p += (size_t)83886080;
  bf16_t* Kr  = (bf16_t*)p; p += (size_t)4194304;
  bf16_t* Vt  = (bf16_t*)p; p += (size_t)4194304;
  float* cosT = (float*)p;  p += (size_t)524288;
  float* sinT = (float*)p;  p += (size_t)524288;

  cvt_f32_bf16<<<8192, 256, 0, stream>>>(x, xb, 2097152);
  cvt_f32_bf16<<<10240, 256, 0, stream>>>(wqkv, wqb, 2621440);
  cvt_f32_bf16<<<4096, 256, 0, stream>>>(wo, wob, 1048576);
  rope_tables<<<512, 256, 0, stream>>>(cosT, sinT);

  // qkv = x @ w_qkv^T   (4096 x 5120 x K=2048): BM=256, BN=320 -> 16x16 = 256 blocks
  gemm8p<8, 5><<<256, 512, 0, stream>>>(xb, wqb, qkv, 4096, 5120, 2048);

  ln_rope<<<4096, 256, 0, stream>>>(qkv, qnw, qnb, knw, knb, cosT, sinT, Qr, Kr);
  vtrans<<<512, 256, 0, stream>>>(qkv, Vt);

  attn<<<512, 256, 0, stream>>>(Qr, Kr, Vt, qkv, ag);

  // out = ag @ w_o^T    (4096 x 2048 x K=2048): BM=128, BN=256 -> 32x8 = 256 blocks
  gemm8p<4, 4><<<256, 512, 0, stream>>>(ag, wob, out, 4096, 2048, 2048);
}